// Round 8
// baseline (49.543 us; speedup 1.0000x reference)
//
#include <hip/hip_runtime.h>
#include <hip/hip_bf16.h>

typedef __attribute__((ext_vector_type(8))) short short8;   // 8 bf16 MFMA A/B frag
typedef __attribute__((ext_vector_type(4))) float fv4;      // MFMA C/D frag
typedef __attribute__((ext_vector_type(4))) int   iv4;      // 16B pack

constexpr int B_ = 16, A_ = 1024, V_ = 1024, D_ = 512;
constexpr int ROWS_A = B_ * A_;              // 16384
constexpr int ROWS_T = 2 * ROWS_A;           // 32768
constexpr size_t BF_ONE = (size_t)ROWS_A * D_ * 2;          // 16 MiB each
constexpr size_t WS_NEED = 2 * BF_ONE + (size_t)ROWS_T * 4; // 32 MiB + 128 KiB

// fp32 -> bf16 round-to-nearest-even
__device__ __forceinline__ unsigned f2bf(float f) {
    unsigned u = __builtin_bit_cast(unsigned, f);
    return (u + 0x7fffu + ((u >> 16) & 1u)) >> 16;
}

// ---------------- Pass 1: fp32 -> bf16 convert + row squared-norms ----------------
__global__ void __launch_bounds__(256)
convert_kernel(const float* __restrict__ audio, const float* __restrict__ visual,
               ushort* __restrict__ abf, ushort* __restrict__ vbf,
               float* __restrict__ normA, float* __restrict__ normV)
{
    const int lane = threadIdx.x & 63;
    const int wv   = (blockIdx.x * 256 + threadIdx.x) >> 6;
    const int nw   = (gridDim.x * 256) >> 6;

    for (int row = wv; row < ROWS_T; row += nw) {
        const float* src; ushort* dst; float* nd; int r;
        if (row < ROWS_A) { src = audio;  dst = abf; nd = normA; r = row; }
        else              { src = visual; dst = vbf; nd = normV; r = row - ROWS_A; }

        const float* p = src + (size_t)r * D_ + lane * 8;   // one wave = one row
        fv4 x0 = *(const fv4*)p;
        fv4 x1 = *(const fv4*)(p + 4);

        float s = 0.f;
#pragma unroll
        for (int i = 0; i < 4; ++i) s += x0[i] * x0[i] + x1[i] * x1[i];

        iv4 w;
        w[0] = (int)(f2bf(x0[0]) | (f2bf(x0[1]) << 16));
        w[1] = (int)(f2bf(x0[2]) | (f2bf(x0[3]) << 16));
        w[2] = (int)(f2bf(x1[0]) | (f2bf(x1[1]) << 16));
        w[3] = (int)(f2bf(x1[2]) | (f2bf(x1[3]) << 16));
        *(iv4*)(dst + (size_t)r * D_ + lane * 8) = w;

#pragma unroll
        for (int m = 1; m < 64; m <<= 1) s += __shfl_xor(s, m, 64);
        if (lane == 0) nd[r] = s;
    }
}

// ---------------- raw-primitive helpers ----------------
__device__ __forceinline__ void gload16(const void* g, void* l) {
    __builtin_amdgcn_global_load_lds((const __attribute__((address_space(1))) void*)g,
                                     (__attribute__((address_space(3))) void*)l,
                                     16, 0, 0);
}
__device__ __forceinline__ unsigned lds_addr(const void* p) {
    return (unsigned)(unsigned long long)(__attribute__((address_space(3))) const char*)p;
}
__device__ __forceinline__ short8 dsr128(unsigned a) {
    short8 r;
    asm volatile("ds_read_b128 %0, %1" : "=v"(r) : "v"(a));
    return r;
}
#define SB0()   __builtin_amdgcn_sched_barrier(0)
#define LGK0()  asm volatile("s_waitcnt lgkmcnt(0)")
#define VMCN(n) asm volatile("s_waitcnt vmcnt(" #n ")")
#define RBAR()  do { SB0(); __builtin_amdgcn_s_barrier(); SB0(); } while (0)

// ---------------- Pass 2: 128x128 bf16 GEMM, depth-2 counted-vmcnt pipeline ----------------
// 256 threads = 4 waves (2M x 2N, 64x64 C-slabs). BK=64, 8 K-steps, dbuf LDS.
// gload_lds staging (linear dest + inverse-swizzled source); 2 blocks/CU.
// Per K-step: [2 compute phases] barrier; STAGE(kt+2); vmcnt(8); barrier.
__global__ void __launch_bounds__(256, 2)
gemm128(const ushort* __restrict__ abf, const ushort* __restrict__ vbf,
        const float* __restrict__ normA, const float* __restrict__ normV,
        float* __restrict__ out)
{
    __shared__ __align__(16) char sA[2][128 * 128];   // [buf][128 rows][64 bf16]
    __shared__ __align__(16) char sB[2][128 * 128];
    __shared__ float lnrm[256];                       // [0..127]=A rows, [128..255]=V rows

    const int t = threadIdx.x, lane = t & 63, w = t >> 6;
    const int wm = w >> 1, wn = w & 1;

    // XCD-bijective swizzle: 1024 blocks; each XCD gets 128 contiguous = 2 batches.
    const int orig = blockIdx.x;
    const int wg   = (orig & 7) * 128 + (orig >> 3);
    const int b = wg >> 6, tile = wg & 63, ab = tile >> 3, vb = tile & 7;

    const ushort* Ag = abf + ((size_t)b * A_ + ab * 128) * D_;
    const ushort* Vg = vbf + ((size_t)b * V_ + vb * 128) * D_;

    // staging: one gload16 wave-issue covers 8 rows x 128 B (linear LDS dest);
    // source pre-swizzled so ds_read-side XOR finds its chunk (involution).
    const int rl = lane >> 3;            // dest row within 8-row group
    const int cs = (lane & 7) ^ rl;      // swizzled source chunk
    const ushort* asrc = Ag + (size_t)(w * 32 + rl) * D_ + cs * 8;
    const ushort* vsrc = Vg + (size_t)(w * 32 + rl) * D_ + cs * 8;

    // wave w stages A rows [w*32, w*32+32) and B rows [w*32, w*32+32): 8 loads
#define STAGE(kt, buf) do {                                           \
        const size_t _ko = (size_t)(kt) * 64;                         \
        char* _da = (char*)sA[buf] + w * 32 * 128;                    \
        char* _db = (char*)sB[buf] + w * 32 * 128;                    \
        gload16(asrc + 0 * 8 * D_ + _ko, _da + 0 * 1024);             \
        gload16(vsrc + 0 * 8 * D_ + _ko, _db + 0 * 1024);             \
        gload16(asrc + 1 * 8 * D_ + _ko, _da + 1 * 1024);             \
        gload16(vsrc + 1 * 8 * D_ + _ko, _db + 1 * 1024);             \
        gload16(asrc + 2 * 8 * D_ + _ko, _da + 2 * 1024);             \
        gload16(vsrc + 2 * 8 * D_ + _ko, _db + 2 * 1024);             \
        gload16(asrc + 3 * 8 * D_ + _ko, _da + 3 * 1024);             \
        gload16(vsrc + 3 * 8 * D_ + _ko, _db + 3 * 1024);             \
    } while (0)

    // ---- norms to LDS (plain sync; before any pipelined loads) ----
    if (t < 128) lnrm[t] = normA[(size_t)b * A_ + ab * 128 + t];
    else         lnrm[t] = normV[(size_t)b * V_ + vb * 128 + (t - 128)];
    __syncthreads();

    // ---- prologue: stage K0, K1; wait K0 (counted: K1 stays in flight) ----
    STAGE(0, 0);
    STAGE(1, 1);
    VMCN(8);
    RBAR();

    fv4 acc[4][4];
#pragma unroll
    for (int m = 0; m < 4; ++m)
#pragma unroll
        for (int n = 0; n < 4; ++n) acc[m][n] = fv4{0.f, 0.f, 0.f, 0.f};

    const int frow = lane & 15, fg = lane >> 4, xk = frow & 7;
    const unsigned cof0 = (unsigned)(((0 + fg) ^ xk) << 4);
    const unsigned cof1 = (unsigned)(((4 + fg) ^ xk) << 4);
    const unsigned baseA = lds_addr(&sA[0][0]);
    const unsigned baseB = lds_addr(&sB[0][0]);
    const unsigned arow = (unsigned)((wm * 64 + frow) * 128);
    const unsigned brow = (unsigned)((wn * 64 + frow) * 128);

#pragma unroll 1
    for (int kt = 0; kt < 8; ++kt) {
        const int cur = kt & 1;
        const unsigned Ab = baseA + (unsigned)cur * 16384u + arow;
        const unsigned Bb = baseB + (unsigned)cur * 16384u + brow;

        short8 av[4][2];
        // ---- phase 0: A m0-3 (8 reads) + B n0-1 (4 reads); 16 MFMA ----
        {
            short8 bv[2][2];
#pragma unroll
            for (int m = 0; m < 4; ++m) {
                av[m][0] = dsr128(Ab + m * 2048 + cof0);
                av[m][1] = dsr128(Ab + m * 2048 + cof1);
            }
#pragma unroll
            for (int n = 0; n < 2; ++n) {
                bv[n][0] = dsr128(Bb + n * 2048 + cof0);
                bv[n][1] = dsr128(Bb + n * 2048 + cof1);
            }
            LGK0(); SB0();
            __builtin_amdgcn_s_setprio(1);
#pragma unroll
            for (int k = 0; k < 2; ++k)
#pragma unroll
                for (int m = 0; m < 4; ++m)
#pragma unroll
                    for (int n = 0; n < 2; ++n)
                        acc[m][n] = __builtin_amdgcn_mfma_f32_16x16x32_bf16(av[m][k], bv[n][k], acc[m][n], 0, 0, 0);
            __builtin_amdgcn_s_setprio(0);
        }
        // ---- phase 1: B n2-3 (4 reads); 16 MFMA (reuse av) ----
        {
            short8 bv[2][2];
#pragma unroll
            for (int n = 0; n < 2; ++n) {
                bv[n][0] = dsr128(Bb + (n + 2) * 2048 + cof0);
                bv[n][1] = dsr128(Bb + (n + 2) * 2048 + cof1);
            }
            LGK0(); SB0();
            __builtin_amdgcn_s_setprio(1);
#pragma unroll
            for (int k = 0; k < 2; ++k)
#pragma unroll
                for (int m = 0; m < 4; ++m)
#pragma unroll
                    for (int n = 0; n < 2; ++n)
                        acc[m][n + 2] = __builtin_amdgcn_mfma_f32_16x16x32_bf16(av[m][k], bv[n][k], acc[m][n + 2], 0, 0, 0);
            __builtin_amdgcn_s_setprio(0);
        }

        if (kt < 7) {
            RBAR();                 // all waves done READING buf[cur]
            if (kt < 6) {
                STAGE(kt + 2, cur); // overwrite buf[cur] with K-step kt+2
                VMCN(8);            // K(kt+1) landed; K(kt+2) stays in flight
            } else {
                VMCN(0);            // last wait: K7 landed
            }
            RBAR();                 // buf[cur^1] valid workgroup-wide
        }
    }

    // ---- fused epilogue: out = sqrt(max(||a||^2 + ||v||^2 - 2*cross, 0)) ----
    float* Ob = out + (size_t)b * A_ * V_ + (size_t)(ab * 128) * V_ + vb * 128;
#pragma unroll
    for (int m = 0; m < 4; ++m) {
#pragma unroll
        for (int n = 0; n < 4; ++n) {
            const int col = wn * 64 + n * 16 + frow;      // C/D: col = lane&15
            const float vsq = lnrm[128 + col];
#pragma unroll
            for (int j = 0; j < 4; ++j) {
                const int row = wm * 64 + m * 16 + fg * 4 + j;   // row=(lane>>4)*4+reg
                float d2 = lnrm[row] + vsq - 2.f * acc[m][n][j];
                Ob[(size_t)row * V_ + col] = sqrtf(fmaxf(d2, 0.f));
            }
        }
    }
#undef STAGE
}

// ---------------- Fallback (ws too small): naive fp32, correct but slow ----------------
__global__ void __launch_bounds__(256)
l2dist_naive(const float* __restrict__ audio, const float* __restrict__ visual,
             float* __restrict__ out)
{
    const size_t idx = (size_t)blockIdx.x * 256 + threadIdx.x;
    const size_t total = (size_t)B_ * A_ * V_;
    if (idx >= total) return;
    const int v = idx & (V_ - 1);
    const int a = (idx >> 10) & (A_ - 1);
    const int b = idx >> 20;
    const float* ap = audio  + ((size_t)b * A_ + a) * D_;
    const float* vp = visual + ((size_t)b * V_ + v) * D_;
    float s = 0.f;
    for (int d = 0; d < D_; ++d) {
        float df = ap[d] - vp[d];
        s += df * df;
    }
    out[idx] = sqrtf(s);
}

extern "C" void kernel_launch(void* const* d_in, const int* in_sizes, int n_in,
                              void* d_out, int out_size, void* d_ws, size_t ws_size,
                              hipStream_t stream) {
    const float* audio  = (const float*)d_in[0];
    const float* visual = (const float*)d_in[1];
    float* out = (float*)d_out;

    if (ws_size >= WS_NEED) {
        char* ws = (char*)d_ws;
        ushort* abf = (ushort*)ws;
        ushort* vbf = (ushort*)(ws + BF_ONE);
        float*  nA  = (float*)(ws + 2 * BF_ONE);
        float*  nV  = nA + ROWS_A;
        convert_kernel<<<2048, 256, 0, stream>>>(audio, visual, abf, vbf, nA, nV);
        gemm128<<<1024, 256, 0, stream>>>(abf, vbf, nA, nV, out);
    } else {
        const size_t total = (size_t)B_ * A_ * V_;
        l2dist_naive<<<(int)((total + 255) / 256), 256, 0, stream>>>(audio, visual, out);
    }
}